// Round 23
// baseline (104.245 us; speedup 1.0000x reference)
//
#include <hip/hip_runtime.h>
#include <hip/hip_bf16.h>

#define BS 2
#define SEQ 2048
#define DIN 1024
#define HID 1024
#define NH 16
#define HD 64
#define M_ROWS (BS*SEQ)
#define NQKV 3072

typedef __attribute__((ext_vector_type(8))) short short8;
typedef __attribute__((ext_vector_type(4))) short short4v;
typedef __attribute__((ext_vector_type(8))) __bf16 bf16x8;
typedef __attribute__((ext_vector_type(4))) float floatx4;

// native cast -> v_cvt_pk_bf16_f32 when paired (RNE)
__device__ __forceinline__ short f2bf(float f) {
  return __builtin_bit_cast(short, (__bf16)f);
}
__device__ __forceinline__ float bf2f(short s) {
  return __uint_as_float(((unsigned)(unsigned short)s) << 16);
}

__device__ __forceinline__ floatx4 mfma16(short8 a, short8 b, floatx4 c) {
  return __builtin_amdgcn_mfma_f32_16x16x32_bf16(
      __builtin_bit_cast(bf16x8, a), __builtin_bit_cast(bf16x8, b), c, 0, 0, 0);
}

__device__ __forceinline__ float exp2fast(float x) {
#if __has_builtin(__builtin_amdgcn_exp2f)
  return __builtin_amdgcn_exp2f(x);
#else
  return exp2f(x);
#endif
}

__device__ __forceinline__ void gload_lds16(const void* g, void* l) {
  __builtin_amdgcn_global_load_lds(
      (const __attribute__((address_space(1))) unsigned int*)g,
      (__attribute__((address_space(3))) unsigned int*)l, 16, 0, 0);
}

// m214-verified LDS layout: 128B rows (power-2) + byte ^= (row&7)<<4, BOTH sides.
__device__ __forceinline__ int swz_off(int row, int colsh) {
  return row * 128 + ((colsh * 2) ^ ((row & 7) << 4));
}

// ---------- merged pre-pass: W transposes (z<4) + x fp32->bf16 (z==4) ----------
__global__ __launch_bounds__(256) void prep_kernel(
    const float* __restrict__ x,
    const float* __restrict__ Wq, const float* __restrict__ Wk,
    const float* __restrict__ Wv, const float* __restrict__ Wmix,
    short* __restrict__ xb, short* __restrict__ Wt, short* __restrict__ Wmixt)
{
  __shared__ float Ws[64][65];
  if (blockIdx.z < 4) {
    const float* src; short* dst;
    switch (blockIdx.z) {
      case 0:  src = Wq;   dst = Wt;                 break;
      case 1:  src = Wk;   dst = Wt + (1u << 20);    break;
      case 2:  src = Wv;   dst = Wt + (2u << 20);    break;
      default: src = Wmix; dst = Wmixt;              break;
    }
    const int n0 = blockIdx.x * 64, k0 = blockIdx.y * 64;
    const int c = threadIdx.x & 63, r0 = threadIdx.x >> 6;
    #pragma unroll
    for (int i = 0; i < 16; ++i) {
      int rr = r0 + 4 * i;
      Ws[rr][c] = src[(size_t)(k0 + rr) * DIN + n0 + c];
    }
    __syncthreads();
    #pragma unroll
    for (int i = 0; i < 16; ++i) {
      int cc = r0 + 4 * i;
      dst[(size_t)(n0 + cc) * DIN + k0 + c] = f2bf(Ws[c][cc]);
    }
  } else {
    const int bb = blockIdx.y * 16 + blockIdx.x;
    const int gid0 = bb * 256 + threadIdx.x;
    const float4* x4 = (const float4*)x;
    #pragma unroll
    for (int it = 0; it < 8; ++it) {
      int gid = gid0 + it * 65536;
      float4 v0 = x4[2 * gid], v1 = x4[2 * gid + 1];
      short8 o;
      o[0] = f2bf(v0.x); o[1] = f2bf(v0.y); o[2] = f2bf(v0.z); o[3] = f2bf(v0.w);
      o[4] = f2bf(v1.x); o[5] = f2bf(v1.y); o[6] = f2bf(v1.z); o[7] = f2bf(v1.w);
      *(short8*)&xb[(size_t)gid * 8] = o;
    }
  }
}

// ---------- GEMM (BK=64, known-good) + T1 bijective XCD swizzle ----------
template<int BM, int BN, bool OUT_F32, bool QKV>
__global__ __launch_bounds__(256) void gemm_kernel(
    const short* __restrict__ A, const short* __restrict__ Bt,
    const float* __restrict__ bias0, const float* __restrict__ bias1,
    const float* __restrict__ bias2, void* __restrict__ Cp,
    short* __restrict__ vt, int Ndim, int Kdim)
{
  constexpr int MT = BM / 32, NT = BN / 32;
  __shared__ short As[BM * 64];
  __shared__ short Bs[BN * 64];
  const int tid = threadIdx.x;
  const int wid = tid >> 6, lane = tid & 63, lg = lane >> 4, lm = lane & 15;
  const int wr = wid >> 1, wc = wid & 1;

  const int nwgx = gridDim.x;
  const int nwg = nwgx * gridDim.y;
  const int idlin = blockIdx.y * nwgx + blockIdx.x;
  const int sw = (idlin & 7) * (nwg >> 3) + (idlin >> 3);
  const int m0 = (sw / nwgx) * BM, n0 = (sw % nwgx) * BN;

  floatx4 acc[MT][NT];
  #pragma unroll
  for (int i = 0; i < MT; ++i)
    #pragma unroll
    for (int j = 0; j < NT; ++j) acc[i][j] = floatx4{0.f, 0.f, 0.f, 0.f};

  for (int k0 = 0; k0 < Kdim; k0 += 64) {
    __syncthreads();
    #pragma unroll
    for (int j = 0; j < BM / 32; ++j) {
      int flat = tid + 256 * j;
      int row = flat >> 3, ch = (flat & 7) ^ (row & 7);
      gload_lds16(A + (size_t)(m0 + row) * Kdim + k0 + ch * 8,
                  (char*)As + wid * 1024 + j * 4096);
    }
    #pragma unroll
    for (int j = 0; j < BN / 32; ++j) {
      int flat = tid + 256 * j;
      int row = flat >> 3, ch = (flat & 7) ^ (row & 7);
      gload_lds16(Bt + (size_t)(n0 + row) * Kdim + k0 + ch * 8,
                  (char*)Bs + wid * 1024 + j * 4096);
    }
    __syncthreads();

    #pragma unroll
    for (int kk = 0; kk < 2; ++kk) {
      short8 a[MT], b[NT];
      #pragma unroll
      for (int mt = 0; mt < MT; ++mt) {
        int row = wr * (BM / 2) + mt * 16 + lm;
        int ch = (kk * 4 + lg) ^ (row & 7);
        a[mt] = *(const short8*)&As[row * 64 + ch * 8];
      }
      #pragma unroll
      for (int nt = 0; nt < NT; ++nt) {
        int row = wc * (BN / 2) + nt * 16 + lm;
        int ch = (kk * 4 + lg) ^ (row & 7);
        b[nt] = *(const short8*)&Bs[row * 64 + ch * 8];
      }
      #pragma unroll
      for (int mt = 0; mt < MT; ++mt)
        #pragma unroll
        for (int nt = 0; nt < NT; ++nt)
          acc[mt][nt] = mfma16(a[mt], b[nt], acc[mt][nt]);
    }
  }

  #pragma unroll
  for (int mt = 0; mt < MT; ++mt) {
    const int row0 = m0 + wr * (BM / 2) + mt * 16 + 4 * lg;
    #pragma unroll
    for (int nt = 0; nt < NT; ++nt) {
      const int col = n0 + wc * (BN / 2) + nt * 16 + lm;
      const float* bp = bias0;
      if (QKV) bp = (col < 1024) ? bias0 : (col < 2048 ? bias1 : bias2);
      const float bv = bp[col & 1023];
      if (QKV && n0 >= 2048) {
        int hd = col - 2048;
        int bb = row0 >> 11, s = row0 & 2047;
        short4v pv;
        #pragma unroll
        for (int r = 0; r < 4; ++r) pv[r] = f2bf(acc[mt][nt][r] + bv);
        *(short4v*)&vt[((size_t)(bb * (NH * HD) + hd)) * SEQ + s] = pv;
      } else {
        #pragma unroll
        for (int r = 0; r < 4; ++r) {
          float v = acc[mt][nt][r] + bv;
          if (OUT_F32) ((float*)Cp)[(size_t)(row0 + r) * Ndim + col] = v;
          else         ((short*)Cp)[(size_t)(row0 + r) * Ndim + col] = f2bf(v);
        }
      }
    }
  }
}

// ---------- split-KV flash attention: CHUNK=8, single-buffer K/V (24 KB LDS ->
// 6 blocks/CU), 2 barriers/tile, launch_bounds(256,4) so NO spills ----------
#define MFIX 12.0f
__global__ __launch_bounds__(256, 4) void attn_kernel(
    const short* __restrict__ qkv, const short* __restrict__ vt,
    short* __restrict__ att, short* __restrict__ pO, float* __restrict__ pml)
{
  __shared__ short Ks[64 * 64];    // [kv][d], XOR-swizzled
  __shared__ short Vs[64 * 64];    // [d][kv], XOR-swizzled
  __shared__ short Ps[4 * 16 * 64];// per-wave P^T strip
  const int tid = threadIdx.x;
  const int wid = tid >> 6, lane = tid & 63, lg = lane >> 4, lm = lane & 15;

  int id = blockIdx.x, x, c;
  if (id < 8)       { x = id;                      c = 0;       }
  else if (id < 24) { int t = id - 8;  x = 8  + (t >> 1); c = t & 1; }
  else if (id < 48) { int t = id - 24; x = 16 + t / 3;    c = t % 3; }
  else              { int t = id - 48; x = 24 + (t >> 2); c = t & 3; }
  const int nch = (x >> 3) + 1;
  const int tb = c * 8;
  const int te = min(tb + 8, x + 1);
  const int q0 = x * 64;
  const int bh = blockIdx.y, b = bh >> 4, h = bh & 15;
  const short* qp = qkv + (size_t)(b * SEQ) * NQKV + h * HD;
  const short* kp = qp + HID;
  const short* vp = vt + (size_t)bh * HD * SEQ;

  // Q fragments (B-operand), pre-scaled by log2(e)/sqrt(D)
  const float cl2 = 0.18033688011112042f;
  const int qrow_g = q0 + wid * 16 + lm;
  short8 qf[2];
  {
    const short* qrow = qp + (size_t)qrow_g * NQKV;
    #pragma unroll
    for (int kk = 0; kk < 2; ++kk) {
      short8 raw = *(const short8*)(qrow + kk * 32 + lg * 8);
      #pragma unroll
      for (int j = 0; j < 8; ++j) qf[kk][j] = f2bf(bf2f(raw[j]) * cl2);
    }
  }

  short8 ones;
  #pragma unroll
  for (int j = 0; j < 8; ++j) ones[j] = (short)0x3F80;

  // ---- hoisted loop-invariant addresses ----
  const int rstage = tid >> 3, c8 = (tid & 7) * 8;
  int soff[2], koff[2][4], pw[4], pr[2];
  #pragma unroll
  for (int i = 0; i < 2; ++i) soff[i] = swz_off(rstage + 32 * i, c8);
  #pragma unroll
  for (int kk = 0; kk < 2; ++kk)
    #pragma unroll
    for (int nt = 0; nt < 4; ++nt)
      koff[kk][nt] = swz_off(nt * 16 + lm, kk * 32 + lg * 8);
  #pragma unroll
  for (int nt = 0; nt < 4; ++nt) pw[nt] = swz_off(lm, nt * 16 + 4 * lg);
  #pragma unroll
  for (int kk = 0; kk < 2; ++kk) pr[kk] = swz_off(lm, kk * 32 + lg * 8);

  const short* kgp[2];
  const short* vgp[2];
  short8 kreg[2], vreg[2];
  #pragma unroll
  for (int i = 0; i < 2; ++i) {
    kgp[i] = kp + (size_t)(tb * 64 + rstage + 32 * i) * NQKV + c8;
    vgp[i] = vp + (size_t)(rstage + 32 * i) * SEQ + tb * 64 + c8;
    kreg[i] = *(const short8*)kgp[i];
    vreg[i] = *(const short8*)vgp[i];
  }

  char* psw = (char*)(Ps + wid * 16 * 64);
  floatx4 o[4];
  floatx4 ol = floatx4{0.f, 0.f, 0.f, 0.f};
  #pragma unroll
  for (int nt = 0; nt < 4; ++nt) o[nt] = floatx4{0.f, 0.f, 0.f, 0.f};

  for (int t = tb; t < te; ++t) {
    __syncthreads();   // previous tile's LDS reads done
    #pragma unroll
    for (int i = 0; i < 2; ++i) {
      *(short8*)((char*)Ks + soff[i]) = kreg[i];
      *(short8*)((char*)Vs + soff[i]) = vreg[i];
    }
    if (t + 1 < te) {
      #pragma unroll
      for (int i = 0; i < 2; ++i) {
        kgp[i] += 64 * NQKV;
        vgp[i] += 64;
        kreg[i] = *(const short8*)kgp[i];
        vreg[i] = *(const short8*)vgp[i];
      }
    }
    __syncthreads();   // staging visible

    // S^T = K Q^T - MFIX
    floatx4 s[4];
    #pragma unroll
    for (int nt = 0; nt < 4; ++nt) s[nt] = floatx4{-MFIX, -MFIX, -MFIX, -MFIX};
    __builtin_amdgcn_s_setprio(1);
    #pragma unroll
    for (int kk = 0; kk < 2; ++kk)
      #pragma unroll
      for (int nt = 0; nt < 4; ++nt)
        s[nt] = mfma16(*(const short8*)((char*)Ks + koff[kk][nt]), qf[kk], s[nt]);
    __builtin_amdgcn_s_setprio(0);

    // causal mask on diagonal tile only
    if (t == x) {
      #pragma unroll
      for (int nt = 0; nt < 4; ++nt)
        #pragma unroll
        for (int r = 0; r < 4; ++r) {
          int kv = t * 64 + nt * 16 + 4 * lg + r;
          if (kv > qrow_g) s[nt][r] = -3e38f;
        }
    }

    // P = exp2(S^T) -> per-wave LDS strip
    #pragma unroll
    for (int nt = 0; nt < 4; ++nt) {
      short4v pv;
      #pragma unroll
      for (int r = 0; r < 4; ++r) pv[r] = f2bf(exp2fast(s[nt][r]));
      *(short4v*)(psw + pw[nt]) = pv;
    }

    // O^T += V^T P^T ; l += 1^T P^T
    #pragma unroll
    for (int kk = 0; kk < 2; ++kk) {
      short8 pf = *(const short8*)(psw + pr[kk]);
      __builtin_amdgcn_s_setprio(1);
      #pragma unroll
      for (int nt = 0; nt < 4; ++nt)
        o[nt] = mfma16(*(const short8*)((char*)Vs + koff[kk][nt]), pf, o[nt]);
      ol = mfma16(ones, pf, ol);
      __builtin_amdgcn_s_setprio(0);
    }
  }

  if (nch == 1) {
    const float linv = 1.0f / ol[0];
    #pragma unroll
    for (int nt = 0; nt < 4; ++nt) {
      short4v ov;
      #pragma unroll
      for (int r = 0; r < 4; ++r) ov[r] = f2bf(o[nt][r] * linv);
      *(short4v*)&att[((size_t)(b * SEQ + qrow_g)) * HID + h * HD + nt * 16 + 4 * lg] = ov;
    }
  } else {
    // slots/bh = 72: x 8-15 -> (x-8)*2 ; 16-23 -> 16+(x-16)*3 ; 24-31 -> 40+(x-24)*4
    int off;
    if (x < 16)      off = (x - 8) * 2;
    else if (x < 24) off = 16 + (x - 16) * 3;
    else             off = 40 + (x - 24) * 4;
    const int slot = bh * 72 + off + c;
    short* po = pO + (size_t)slot * 4096;
    const int ql = wid * 16 + lm;
    #pragma unroll
    for (int nt = 0; nt < 4; ++nt) {
      short4v ov;
      #pragma unroll
      for (int r = 0; r < 4; ++r) ov[r] = f2bf(o[nt][r]);
      *(short4v*)&po[ql * 64 + nt * 16 + 4 * lg] = ov;
    }
    if (lane < 16) {
      pml[slot * 128 + 64 + ql] = ol[0];
    }
  }
}

// ---------- combine partials (fixed shift -> plain sums): grid (24, 32) ----------
__global__ __launch_bounds__(256) void combine_kernel(
    const short* __restrict__ pO, const float* __restrict__ pml,
    short* __restrict__ att)
{
  const int x = 8 + blockIdx.x;            // x 8..31
  const int bh = blockIdx.y, b = bh >> 4, h = bh & 15;
  const int nch = (x >> 3) + 1;            // 2..4
  const int tid = threadIdx.x;
  const int row = tid >> 2, d0 = (tid & 3) * 16;
  int off;
  if (x < 16)      off = (x - 8) * 2;
  else if (x < 24) off = 16 + (x - 16) * 3;
  else             off = 40 + (x - 24) * 4;
  const int base_slot = bh * 72 + off;

  float L = 0.f;
  for (int cc = 0; cc < nch; ++cc)
    L += pml[(base_slot + cc) * 128 + 64 + row];
  const float inv = 1.0f / L;

  float acc[16];
  #pragma unroll
  for (int j = 0; j < 16; ++j) acc[j] = 0.f;
  for (int cc = 0; cc < nch; ++cc) {
    const short* po = pO + (size_t)(base_slot + cc) * 4096 + row * 64 + d0;
    short8 v0 = *(const short8*)po, v1 = *(const short8*)(po + 8);
    #pragma unroll
    for (int j = 0; j < 8; ++j) {
      acc[j]     += bf2f(v0[j]);
      acc[j + 8] += bf2f(v1[j]);
    }
  }
  short8 o0, o1;
  #pragma unroll
  for (int j = 0; j < 8; ++j) {
    o0[j] = f2bf(acc[j] * inv);
    o1[j] = f2bf(acc[j + 8] * inv);
  }
  short* dst = att + ((size_t)(b * SEQ + x * 64 + row)) * HID + h * HD + d0;
  *(short8*)dst = o0;
  *(short8*)(dst + 8) = o1;
}

extern "C" void kernel_launch(void* const* d_in, const int* in_sizes, int n_in,
                              void* d_out, int out_size, void* d_ws, size_t ws_size,
                              hipStream_t stream) {
  (void)in_sizes; (void)n_in; (void)out_size; (void)ws_size;
  const float* x    = (const float*)d_in[0];
  const float* Wq   = (const float*)d_in[1];
  const float* bq   = (const float*)d_in[2];
  const float* Wk   = (const float*)d_in[3];
  const float* bk   = (const float*)d_in[4];
  const float* Wv   = (const float*)d_in[5];
  const float* bv   = (const float*)d_in[6];
  const float* Wmix = (const float*)d_in[7];
  const float* bmix = (const float*)d_in[8];
  float* out = (float*)d_out;

  char* w = (char*)d_ws;
  short* xb      = (short*)w; w += (size_t)8 << 20;
  short* Wt      = (short*)w; w += (size_t)6 << 20;
  short* Wmixt   = (short*)w; w += (size_t)2 << 20;
  short* qkvb    = (short*)w; w += (size_t)24 << 20;
  short* vtb     = (short*)w; w += (size_t)8 << 20;
  short* ab      = (short*)w; w += (size_t)8 << 20;
  short* pO      = (short*)w; w += (size_t)72 * 32 * 4096 * 2;
  float* pml     = (float*)w;

  hipLaunchKernelGGL(prep_kernel, dim3(16, 16, 5), dim3(256), 0, stream,
                     x, Wq, Wk, Wv, Wmix, xb, Wt, Wmixt);

  hipLaunchKernelGGL((gemm_kernel<128, 128, false, true>), dim3(NQKV / 128, M_ROWS / 128),
                     dim3(256), 0, stream, xb, Wt, bq, bk, bv, (void*)qkvb, vtb, NQKV, DIN);

  hipLaunchKernelGGL(attn_kernel, dim3(80, BS * NH), dim3(256), 0, stream,
                     qkvb, vtb, ab, pO, pml);
  hipLaunchKernelGGL(combine_kernel, dim3(24, BS * NH), dim3(256), 0, stream,
                     pO, pml, ab);

  hipLaunchKernelGGL((gemm_kernel<128, 128, true, false>), dim3(HID / 128, M_ROWS / 128),
                     dim3(256), 0, stream, ab, Wmixt, bmix, bmix, bmix, (void*)out,
                     (short*)nullptr, HID, DIN);
}

// Round 24
// 99.485 us; speedup vs baseline: 1.0478x; 1.0478x over previous
//
#include <hip/hip_runtime.h>
#include <hip/hip_bf16.h>

#define BS 2
#define SEQ 2048
#define DIN 1024
#define HID 1024
#define NH 16
#define HD 64
#define M_ROWS (BS*SEQ)
#define NQKV 3072

typedef __attribute__((ext_vector_type(8))) short short8;
typedef __attribute__((ext_vector_type(4))) short short4v;
typedef __attribute__((ext_vector_type(8))) __bf16 bf16x8;
typedef __attribute__((ext_vector_type(4))) float floatx4;

// native cast -> v_cvt_pk_bf16_f32 when paired (RNE)
__device__ __forceinline__ short f2bf(float f) {
  return __builtin_bit_cast(short, (__bf16)f);
}
__device__ __forceinline__ float bf2f(short s) {
  return __uint_as_float(((unsigned)(unsigned short)s) << 16);
}

__device__ __forceinline__ floatx4 mfma16(short8 a, short8 b, floatx4 c) {
  return __builtin_amdgcn_mfma_f32_16x16x32_bf16(
      __builtin_bit_cast(bf16x8, a), __builtin_bit_cast(bf16x8, b), c, 0, 0, 0);
}

__device__ __forceinline__ float exp2fast(float x) {
#if __has_builtin(__builtin_amdgcn_exp2f)
  return __builtin_amdgcn_exp2f(x);
#else
  return exp2f(x);
#endif
}

__device__ __forceinline__ void gload_lds16(const void* g, void* l) {
  __builtin_amdgcn_global_load_lds(
      (const __attribute__((address_space(1))) unsigned int*)g,
      (__attribute__((address_space(3))) unsigned int*)l, 16, 0, 0);
}

// m214-verified LDS layout: 128B rows (power-2) + byte ^= (row&7)<<4, BOTH sides.
__device__ __forceinline__ int swz_off(int row, int colsh) {
  return row * 128 + ((colsh * 2) ^ ((row & 7) << 4));
}

// ---------- merged pre-pass: W transposes (z<4) + x fp32->bf16 (z==4) ----------
__global__ __launch_bounds__(256) void prep_kernel(
    const float* __restrict__ x,
    const float* __restrict__ Wq, const float* __restrict__ Wk,
    const float* __restrict__ Wv, const float* __restrict__ Wmix,
    short* __restrict__ xb, short* __restrict__ Wt, short* __restrict__ Wmixt)
{
  __shared__ float Ws[64][65];
  if (blockIdx.z < 4) {
    const float* src; short* dst;
    switch (blockIdx.z) {
      case 0:  src = Wq;   dst = Wt;                 break;
      case 1:  src = Wk;   dst = Wt + (1u << 20);    break;
      case 2:  src = Wv;   dst = Wt + (2u << 20);    break;
      default: src = Wmix; dst = Wmixt;              break;
    }
    const int n0 = blockIdx.x * 64, k0 = blockIdx.y * 64;
    const int c = threadIdx.x & 63, r0 = threadIdx.x >> 6;
    #pragma unroll
    for (int i = 0; i < 16; ++i) {
      int rr = r0 + 4 * i;
      Ws[rr][c] = src[(size_t)(k0 + rr) * DIN + n0 + c];
    }
    __syncthreads();
    #pragma unroll
    for (int i = 0; i < 16; ++i) {
      int cc = r0 + 4 * i;
      dst[(size_t)(n0 + cc) * DIN + k0 + c] = f2bf(Ws[c][cc]);
    }
  } else {
    const int bb = blockIdx.y * 16 + blockIdx.x;
    const int gid0 = bb * 256 + threadIdx.x;
    const float4* x4 = (const float4*)x;
    #pragma unroll
    for (int it = 0; it < 8; ++it) {
      int gid = gid0 + it * 65536;
      float4 v0 = x4[2 * gid], v1 = x4[2 * gid + 1];
      short8 o;
      o[0] = f2bf(v0.x); o[1] = f2bf(v0.y); o[2] = f2bf(v0.z); o[3] = f2bf(v0.w);
      o[4] = f2bf(v1.x); o[5] = f2bf(v1.y); o[6] = f2bf(v1.z); o[7] = f2bf(v1.w);
      *(short8*)&xb[(size_t)gid * 8] = o;
    }
  }
}

// ---------- GEMM (BK=64, known-good) + T1 bijective XCD swizzle ----------
template<int BM, int BN, bool OUT_F32, bool QKV>
__global__ __launch_bounds__(256) void gemm_kernel(
    const short* __restrict__ A, const short* __restrict__ Bt,
    const float* __restrict__ bias0, const float* __restrict__ bias1,
    const float* __restrict__ bias2, void* __restrict__ Cp,
    short* __restrict__ vt, int Ndim, int Kdim)
{
  constexpr int MT = BM / 32, NT = BN / 32;
  __shared__ short As[BM * 64];
  __shared__ short Bs[BN * 64];
  const int tid = threadIdx.x;
  const int wid = tid >> 6, lane = tid & 63, lg = lane >> 4, lm = lane & 15;
  const int wr = wid >> 1, wc = wid & 1;

  const int nwgx = gridDim.x;
  const int nwg = nwgx * gridDim.y;
  const int idlin = blockIdx.y * nwgx + blockIdx.x;
  const int sw = (idlin & 7) * (nwg >> 3) + (idlin >> 3);
  const int m0 = (sw / nwgx) * BM, n0 = (sw % nwgx) * BN;

  floatx4 acc[MT][NT];
  #pragma unroll
  for (int i = 0; i < MT; ++i)
    #pragma unroll
    for (int j = 0; j < NT; ++j) acc[i][j] = floatx4{0.f, 0.f, 0.f, 0.f};

  for (int k0 = 0; k0 < Kdim; k0 += 64) {
    __syncthreads();
    #pragma unroll
    for (int j = 0; j < BM / 32; ++j) {
      int flat = tid + 256 * j;
      int row = flat >> 3, ch = (flat & 7) ^ (row & 7);
      gload_lds16(A + (size_t)(m0 + row) * Kdim + k0 + ch * 8,
                  (char*)As + wid * 1024 + j * 4096);
    }
    #pragma unroll
    for (int j = 0; j < BN / 32; ++j) {
      int flat = tid + 256 * j;
      int row = flat >> 3, ch = (flat & 7) ^ (row & 7);
      gload_lds16(Bt + (size_t)(n0 + row) * Kdim + k0 + ch * 8,
                  (char*)Bs + wid * 1024 + j * 4096);
    }
    __syncthreads();

    #pragma unroll
    for (int kk = 0; kk < 2; ++kk) {
      short8 a[MT], b[NT];
      #pragma unroll
      for (int mt = 0; mt < MT; ++mt) {
        int row = wr * (BM / 2) + mt * 16 + lm;
        int ch = (kk * 4 + lg) ^ (row & 7);
        a[mt] = *(const short8*)&As[row * 64 + ch * 8];
      }
      #pragma unroll
      for (int nt = 0; nt < NT; ++nt) {
        int row = wc * (BN / 2) + nt * 16 + lm;
        int ch = (kk * 4 + lg) ^ (row & 7);
        b[nt] = *(const short8*)&Bs[row * 64 + ch * 8];
      }
      #pragma unroll
      for (int mt = 0; mt < MT; ++mt)
        #pragma unroll
        for (int nt = 0; nt < NT; ++nt)
          acc[mt][nt] = mfma16(a[mt], b[nt], acc[mt][nt]);
    }
  }

  #pragma unroll
  for (int mt = 0; mt < MT; ++mt) {
    const int row0 = m0 + wr * (BM / 2) + mt * 16 + 4 * lg;
    #pragma unroll
    for (int nt = 0; nt < NT; ++nt) {
      const int col = n0 + wc * (BN / 2) + nt * 16 + lm;
      const float* bp = bias0;
      if (QKV) bp = (col < 1024) ? bias0 : (col < 2048 ? bias1 : bias2);
      const float bv = bp[col & 1023];
      if (QKV && n0 >= 2048) {
        int hd = col - 2048;
        int bb = row0 >> 11, s = row0 & 2047;
        short4v pv;
        #pragma unroll
        for (int r = 0; r < 4; ++r) pv[r] = f2bf(acc[mt][nt][r] + bv);
        *(short4v*)&vt[((size_t)(bb * (NH * HD) + hd)) * SEQ + s] = pv;
      } else {
        #pragma unroll
        for (int r = 0; r < 4; ++r) {
          float v = acc[mt][nt][r] + bv;
          if (OUT_F32) ((float*)Cp)[(size_t)(row0 + r) * Ndim + col] = v;
          else         ((short*)Cp)[(size_t)(row0 + r) * Ndim + col] = f2bf(v);
        }
      }
    }
  }
}

// ---------- split-KV flash attention: CHUNK=8, single-buffer K/V (24 KB LDS ->
// 6 blocks/CU), 2 barriers/tile, launch_bounds(256,4) so NO spills ----------
#define MFIX 12.0f
__global__ __launch_bounds__(256, 4) void attn_kernel(
    const short* __restrict__ qkv, const short* __restrict__ vt,
    short* __restrict__ att, short* __restrict__ pO, float* __restrict__ pml)
{
  __shared__ short Ks[64 * 64];    // [kv][d], XOR-swizzled
  __shared__ short Vs[64 * 64];    // [d][kv], XOR-swizzled
  __shared__ short Ps[4 * 16 * 64];// per-wave P^T strip
  const int tid = threadIdx.x;
  const int wid = tid >> 6, lane = tid & 63, lg = lane >> 4, lm = lane & 15;

  int id = blockIdx.x, x, c;
  if (id < 8)       { x = id;                      c = 0;       }
  else if (id < 24) { int t = id - 8;  x = 8  + (t >> 1); c = t & 1; }
  else if (id < 48) { int t = id - 24; x = 16 + t / 3;    c = t % 3; }
  else              { int t = id - 48; x = 24 + (t >> 2); c = t & 3; }
  const int nch = (x >> 3) + 1;
  const int tb = c * 8;
  const int te = min(tb + 8, x + 1);
  const int q0 = x * 64;
  const int bh = blockIdx.y, b = bh >> 4, h = bh & 15;
  const short* qp = qkv + (size_t)(b * SEQ) * NQKV + h * HD;
  const short* kp = qp + HID;
  const short* vp = vt + (size_t)bh * HD * SEQ;

  // Q fragments (B-operand), pre-scaled by log2(e)/sqrt(D)
  const float cl2 = 0.18033688011112042f;
  const int qrow_g = q0 + wid * 16 + lm;
  short8 qf[2];
  {
    const short* qrow = qp + (size_t)qrow_g * NQKV;
    #pragma unroll
    for (int kk = 0; kk < 2; ++kk) {
      short8 raw = *(const short8*)(qrow + kk * 32 + lg * 8);
      #pragma unroll
      for (int j = 0; j < 8; ++j) qf[kk][j] = f2bf(bf2f(raw[j]) * cl2);
    }
  }

  short8 ones;
  #pragma unroll
  for (int j = 0; j < 8; ++j) ones[j] = (short)0x3F80;

  // ---- hoisted loop-invariant addresses ----
  const int rstage = tid >> 3, c8 = (tid & 7) * 8;
  int soff[2], koff[2][4], pw[4], pr[2];
  #pragma unroll
  for (int i = 0; i < 2; ++i) soff[i] = swz_off(rstage + 32 * i, c8);
  #pragma unroll
  for (int kk = 0; kk < 2; ++kk)
    #pragma unroll
    for (int nt = 0; nt < 4; ++nt)
      koff[kk][nt] = swz_off(nt * 16 + lm, kk * 32 + lg * 8);
  #pragma unroll
  for (int nt = 0; nt < 4; ++nt) pw[nt] = swz_off(lm, nt * 16 + 4 * lg);
  #pragma unroll
  for (int kk = 0; kk < 2; ++kk) pr[kk] = swz_off(lm, kk * 32 + lg * 8);

  const short* kgp[2];
  const short* vgp[2];
  short8 kreg[2], vreg[2];
  #pragma unroll
  for (int i = 0; i < 2; ++i) {
    kgp[i] = kp + (size_t)(tb * 64 + rstage + 32 * i) * NQKV + c8;
    vgp[i] = vp + (size_t)(rstage + 32 * i) * SEQ + tb * 64 + c8;
    kreg[i] = *(const short8*)kgp[i];
    vreg[i] = *(const short8*)vgp[i];
  }

  char* psw = (char*)(Ps + wid * 16 * 64);
  floatx4 o[4];
  floatx4 ol = floatx4{0.f, 0.f, 0.f, 0.f};
  #pragma unroll
  for (int nt = 0; nt < 4; ++nt) o[nt] = floatx4{0.f, 0.f, 0.f, 0.f};

  for (int t = tb; t < te; ++t) {
    __syncthreads();   // previous tile's LDS reads done
    #pragma unroll
    for (int i = 0; i < 2; ++i) {
      *(short8*)((char*)Ks + soff[i]) = kreg[i];
      *(short8*)((char*)Vs + soff[i]) = vreg[i];
    }
    if (t + 1 < te) {
      #pragma unroll
      for (int i = 0; i < 2; ++i) {
        kgp[i] += 64 * NQKV;
        vgp[i] += 64;
        kreg[i] = *(const short8*)kgp[i];
        vreg[i] = *(const short8*)vgp[i];
      }
    }
    __syncthreads();   // staging visible

    // S^T = K Q^T - MFIX
    floatx4 s[4];
    #pragma unroll
    for (int nt = 0; nt < 4; ++nt) s[nt] = floatx4{-MFIX, -MFIX, -MFIX, -MFIX};
    __builtin_amdgcn_s_setprio(1);
    #pragma unroll
    for (int kk = 0; kk < 2; ++kk)
      #pragma unroll
      for (int nt = 0; nt < 4; ++nt)
        s[nt] = mfma16(*(const short8*)((char*)Ks + koff[kk][nt]), qf[kk], s[nt]);
    __builtin_amdgcn_s_setprio(0);

    // causal mask on diagonal tile only
    if (t == x) {
      #pragma unroll
      for (int nt = 0; nt < 4; ++nt)
        #pragma unroll
        for (int r = 0; r < 4; ++r) {
          int kv = t * 64 + nt * 16 + 4 * lg + r;
          if (kv > qrow_g) s[nt][r] = -3e38f;
        }
    }

    // P = exp2(S^T) -> per-wave LDS strip
    #pragma unroll
    for (int nt = 0; nt < 4; ++nt) {
      short4v pv;
      #pragma unroll
      for (int r = 0; r < 4; ++r) pv[r] = f2bf(exp2fast(s[nt][r]));
      *(short4v*)(psw + pw[nt]) = pv;
    }

    // O^T += V^T P^T ; l += 1^T P^T
    #pragma unroll
    for (int kk = 0; kk < 2; ++kk) {
      short8 pf = *(const short8*)(psw + pr[kk]);
      __builtin_amdgcn_s_setprio(1);
      #pragma unroll
      for (int nt = 0; nt < 4; ++nt)
        o[nt] = mfma16(*(const short8*)((char*)Vs + koff[kk][nt]), pf, o[nt]);
      ol = mfma16(ones, pf, ol);
      __builtin_amdgcn_s_setprio(0);
    }
  }

  if (nch == 1) {
    const float linv = 1.0f / ol[0];
    #pragma unroll
    for (int nt = 0; nt < 4; ++nt) {
      short4v ov;
      #pragma unroll
      for (int r = 0; r < 4; ++r) ov[r] = f2bf(o[nt][r] * linv);
      *(short4v*)&att[((size_t)(b * SEQ + qrow_g)) * HID + h * HD + nt * 16 + 4 * lg] = ov;
    }
  } else {
    // slots/bh = 72: x 8-15 -> (x-8)*2 ; 16-23 -> 16+(x-16)*3 ; 24-31 -> 40+(x-24)*4
    int off;
    if (x < 16)      off = (x - 8) * 2;
    else if (x < 24) off = 16 + (x - 16) * 3;
    else             off = 40 + (x - 24) * 4;
    const int slot = bh * 72 + off + c;
    short* po = pO + (size_t)slot * 4096;
    const int ql = wid * 16 + lm;
    #pragma unroll
    for (int nt = 0; nt < 4; ++nt) {
      short4v ov;
      #pragma unroll
      for (int r = 0; r < 4; ++r) ov[r] = f2bf(o[nt][r]);
      *(short4v*)&po[ql * 64 + nt * 16 + 4 * lg] = ov;
    }
    if (lane < 16) {
      pml[slot * 128 + 64 + ql] = ol[0];
    }
  }
}

// ---------- combine partials (fixed shift -> plain sums): grid (24, 32) ----------
__global__ __launch_bounds__(256) void combine_kernel(
    const short* __restrict__ pO, const float* __restrict__ pml,
    short* __restrict__ att)
{
  const int x = 8 + blockIdx.x;            // x 8..31
  const int bh = blockIdx.y, b = bh >> 4, h = bh & 15;
  const int nch = (x >> 3) + 1;            // 2..4
  const int tid = threadIdx.x;
  const int row = tid >> 2, d0 = (tid & 3) * 16;
  int off;
  if (x < 16)      off = (x - 8) * 2;
  else if (x < 24) off = 16 + (x - 16) * 3;
  else             off = 40 + (x - 24) * 4;
  const int base_slot = bh * 72 + off;

  float L = 0.f;
  for (int cc = 0; cc < nch; ++cc)
    L += pml[(base_slot + cc) * 128 + 64 + row];
  const float inv = 1.0f / L;

  float acc[16];
  #pragma unroll
  for (int j = 0; j < 16; ++j) acc[j] = 0.f;
  for (int cc = 0; cc < nch; ++cc) {
    const short* po = pO + (size_t)(base_slot + cc) * 4096 + row * 64 + d0;
    short8 v0 = *(const short8*)po, v1 = *(const short8*)(po + 8);
    #pragma unroll
    for (int j = 0; j < 8; ++j) {
      acc[j]     += bf2f(v0[j]);
      acc[j + 8] += bf2f(v1[j]);
    }
  }
  short8 o0, o1;
  #pragma unroll
  for (int j = 0; j < 8; ++j) {
    o0[j] = f2bf(acc[j] * inv);
    o1[j] = f2bf(acc[j + 8] * inv);
  }
  short* dst = att + ((size_t)(b * SEQ + x * 64 + row)) * HID + h * HD + d0;
  *(short8*)dst = o0;
  *(short8*)(dst + 8) = o1;
}

extern "C" void kernel_launch(void* const* d_in, const int* in_sizes, int n_in,
                              void* d_out, int out_size, void* d_ws, size_t ws_size,
                              hipStream_t stream) {
  (void)in_sizes; (void)n_in; (void)out_size; (void)ws_size;
  const float* x    = (const float*)d_in[0];
  const float* Wq   = (const float*)d_in[1];
  const float* bq   = (const float*)d_in[2];
  const float* Wk   = (const float*)d_in[3];
  const float* bk   = (const float*)d_in[4];
  const float* Wv   = (const float*)d_in[5];
  const float* bv   = (const float*)d_in[6];
  const float* Wmix = (const float*)d_in[7];
  const float* bmix = (const float*)d_in[8];
  float* out = (float*)d_out;

  char* w = (char*)d_ws;
  short* xb      = (short*)w; w += (size_t)8 << 20;
  short* Wt      = (short*)w; w += (size_t)6 << 20;
  short* Wmixt   = (short*)w; w += (size_t)2 << 20;
  short* qkvb    = (short*)w; w += (size_t)24 << 20;
  short* vtb     = (short*)w; w += (size_t)8 << 20;
  short* ab      = (short*)w; w += (size_t)8 << 20;
  short* pO      = (short*)w; w += (size_t)72 * 32 * 4096 * 2;
  float* pml     = (float*)w;

  hipLaunchKernelGGL(prep_kernel, dim3(16, 16, 5), dim3(256), 0, stream,
                     x, Wq, Wk, Wv, Wmix, xb, Wt, Wmixt);

  hipLaunchKernelGGL((gemm_kernel<128, 128, false, true>), dim3(NQKV / 128, M_ROWS / 128),
                     dim3(256), 0, stream, xb, Wt, bq, bk, bv, (void*)qkvb, vtb, NQKV, DIN);

  hipLaunchKernelGGL(attn_kernel, dim3(80, BS * NH), dim3(256), 0, stream,
                     qkvb, vtb, ab, pO, pml);
  hipLaunchKernelGGL(combine_kernel, dim3(24, BS * NH), dim3(256), 0, stream,
                     pO, pml, ab);

  hipLaunchKernelGGL((gemm_kernel<64, 128, true, false>), dim3(HID / 128, M_ROWS / 64),
                     dim3(256), 0, stream, ab, Wmixt, bmix, bmix, bmix, (void*)out,
                     (short*)nullptr, HID, DIN);
}